// Round 7
// baseline (1613.157 us; speedup 1.0000x reference)
//
#include <hip/hip_runtime.h>
#include <math.h>

typedef short  bf16x8 __attribute__((ext_vector_type(8)));
typedef float  f32x4  __attribute__((ext_vector_type(4)));

__device__ __forceinline__ unsigned short bf16_rn(float x) {
    unsigned u = __float_as_uint(x);
    u += 0x7fffu + ((u >> 16) & 1u);
    return (unsigned short)(u >> 16);
}
__device__ __forceinline__ float bf16f(unsigned short h) {
    return __uint_as_float(((unsigned)h) << 16);
}
// monotone float<->uint encoding for atomicMax on floats
__device__ __forceinline__ unsigned fenc(float v) {
    int i = __float_as_int(v);
    return (i >= 0) ? ((unsigned)i | 0x80000000u) : ~((unsigned)i);
}
__device__ __forceinline__ float fdec(unsigned u) {
    int i = (u & 0x80000000u) ? (int)(u & 0x7fffffffu) : ~((int)u);
    return __int_as_float(i);
}

// async global->LDS, 16B per lane. HW writes LDS at wave-uniform base + lane*16
// (m104/m108); per-lane GLOBAL address carries the layout permutation (m173).
__device__ __forceinline__ void gl2lds16(const void* gptr, void* lptr) {
    __builtin_amdgcn_global_load_lds(
        (const __attribute__((address_space(1))) unsigned int*)(unsigned long long)gptr,
        (__attribute__((address_space(3))) unsigned int*)(unsigned int)(unsigned long long)lptr,
        16, 0, 0);
}

// ==================== MFMA split-bf16 GEMM =================================
// C = scale*(A@B) [+ bias], computed as Ah*Bh + Ah*Bl + Al*Bh on bf16 MFMA.
// R7 structure: block tile 256x256, 512 threads = 8 waves (2 x 4), wave tile
// 128x64 (8x4 of 16x16x32), BK=32. R6 post-mortem: 64x64 wave tiles were
// LDS-READ-BW-bound (128 KB/CU/K-step at ~85 B/cy = 1540cy vs 466cy MFMA
// -> 30% MfmaUtil exactly as measured). 128x64 doubles MFMA per LDS byte:
// per-CU 932cy MFMA vs ~1540-2260cy LDS -> ceiling ~45-60%.
// Double-buffered LDS (128 KB), R4-verified 2-barrier K-step, counted
// vmcnt(8) (8 gload_lds/wave/tile), vmcnt(0) only at tail. A-frags are
// STREAMED per-mi (peak ~200 VGPR, no spill at the 256 cap).
// LDS per array: [blk 16][kg 4][row 16][8 bf16] = 16 KB/buf.
// OUTM: 0 = fp32 C (o1)    1 = qkv epilogue (o1..o5 = Qh,Ql,Kh,Kl,Vfp32)
//       2 = hi/lo bf16 (o1,o2)
// ROWMAX (OUTM=0): atomicMax per-row max of scaled C into (unsigned*)o2.
// ROWSCALE (OUTM=2): per-row scale from (const float*)o3 [z*1024+row].
template<int OUTM, bool HAS_BIAS, bool ROWMAX, bool ROWSCALE>
__global__ __launch_bounds__(512, 2)
void mgemm(const unsigned short* __restrict__ Ah_, const unsigned short* __restrict__ Al_,
           const unsigned short* __restrict__ Bh_, const unsigned short* __restrict__ Bl_,
           const float* __restrict__ bias,
           void* o1, void* o2, void* o3, void* o4, void* o5,
           int K, int lda, int ldc,
           long long sA, long long sB, long long sC, float scale)
{
    const int tid = threadIdx.x;
    const int bm = blockIdx.y * 256;
    const int bn = blockIdx.x * 256;
    const long long z = blockIdx.z;

    const unsigned short* Ahu = Ah_ + z * sA;
    const unsigned short* Alu = Al_ + z * sA;
    const unsigned short* Bhu = Bh_ + z * sB;
    const unsigned short* Blu = Bl_ + z * sB;

    __shared__ unsigned short LA_h[2][8192], LA_l[2][8192];   // 16 blks x 512
    __shared__ unsigned short LB_h[2][8192], LB_l[2][8192];

    const int wv = tid >> 6, lane = tid & 63;
    const int wr = wv >> 2, wc = wv & 3;                  // 2 x 4 wave grid
    const int fro = (lane >> 4) * 128 + (lane & 15) * 8;  // frag offset in blk

    // staging: wave wv stages A blks {wv, wv+8}, B blks {wv, wv+8};
    // lane l -> (kg=l>>4, row=l&15): HW linear lane*16B write == [kg][row][8]
    const int srow = lane & 15, skg = lane >> 4;
    const size_t gaA0 = (size_t)(bm + 16 * wv       + srow) * lda + skg * 8;
    const size_t gaA1 = (size_t)(bm + 16 * (wv + 8) + srow) * lda + skg * 8;
    const size_t gaB0 = (size_t)(bn + 16 * wv       + srow) * lda + skg * 8;
    const size_t gaB1 = (size_t)(bn + 16 * (wv + 8) + srow) * lda + skg * 8;
    const int lo0 = wv * 512, lo1 = (wv + 8) * 512;

    auto stage = [&](int bb, int k0) {   // 8 x global_load_lds_dwordx4 / wave
        gl2lds16(&Ahu[gaA0 + k0], &LA_h[bb][lo0]);
        gl2lds16(&Ahu[gaA1 + k0], &LA_h[bb][lo1]);
        gl2lds16(&Alu[gaA0 + k0], &LA_l[bb][lo0]);
        gl2lds16(&Alu[gaA1 + k0], &LA_l[bb][lo1]);
        gl2lds16(&Bhu[gaB0 + k0], &LB_h[bb][lo0]);
        gl2lds16(&Bhu[gaB1 + k0], &LB_h[bb][lo1]);
        gl2lds16(&Blu[gaB0 + k0], &LB_l[bb][lo0]);
        gl2lds16(&Blu[gaB1 + k0], &LB_l[bb][lo1]);
    };

    f32x4 acc[8][4];
#pragma unroll
    for (int i = 0; i < 8; ++i)
#pragma unroll
        for (int j = 0; j < 4; ++j) acc[i][j] = (f32x4){0.f, 0.f, 0.f, 0.f};

    const int nkt = K >> 5;      // >= 24 at all call sites
    stage(0, 0);
    stage(1, 32);
    int cur = 0;
    for (int kt = 0; kt < nkt; ++kt) {
        // wait for buf[cur]'s 8 loads; the newer 8 stay in flight
        if (kt < nkt - 1) {
            asm volatile("s_waitcnt vmcnt(8)" ::: "memory");
        } else {
            asm volatile("s_waitcnt vmcnt(0)" ::: "memory");
        }
        __builtin_amdgcn_sched_barrier(0);
        __builtin_amdgcn_s_barrier();            // buf[cur] landed
        __builtin_amdgcn_sched_barrier(0);

        // ---- B fragments (held), A fragments streamed per-mi ----
        bf16x8 bhf[4], blf[4];
#pragma unroll
        for (int ni = 0; ni < 4; ++ni) {
            int off = (wc * 4 + ni) * 512 + fro;
            bhf[ni] = *(const bf16x8*)&LB_h[cur][off];
            blf[ni] = *(const bf16x8*)&LB_l[cur][off];
        }
        __builtin_amdgcn_s_setprio(1);
#pragma unroll
        for (int mi = 0; mi < 8; ++mi) {
            int off = (wr * 8 + mi) * 512 + fro;
            bf16x8 ah = *(const bf16x8*)&LA_h[cur][off];
            bf16x8 al = *(const bf16x8*)&LA_l[cur][off];
#pragma unroll
            for (int ni = 0; ni < 4; ++ni) {
                f32x4 a = acc[mi][ni];
                a = __builtin_amdgcn_mfma_f32_16x16x32_bf16(ah, bhf[ni], a, 0, 0, 0);
                a = __builtin_amdgcn_mfma_f32_16x16x32_bf16(ah, blf[ni], a, 0, 0, 0);
                a = __builtin_amdgcn_mfma_f32_16x16x32_bf16(al, bhf[ni], a, 0, 0, 0);
                acc[mi][ni] = a;
            }
        }
        __builtin_amdgcn_s_setprio(0);
        asm volatile("s_waitcnt lgkmcnt(0)" ::: "memory");
        __builtin_amdgcn_sched_barrier(0);
        __builtin_amdgcn_s_barrier();            // all waves done reading buf
        __builtin_amdgcn_sched_barrier(0);
        if (kt + 2 < nkt) stage(cur, (kt + 2) << 5);   // restage same buf
        cur ^= 1;
    }

    // ---- epilogue: C/D layout col=lane&15, row=(lane>>4)*4+r ----
#pragma unroll
    for (int mi = 0; mi < 8; ++mi) {
#pragma unroll
        for (int ni = 0; ni < 4; ++ni) {
            const int grow0 = bm + wr * 128 + mi * 16 + ((lane >> 4) << 2);
            const int gcol  = bn + wc * 64 + ni * 16 + (lane & 15);
            float bb = HAS_BIAS ? bias[gcol] : 0.f;
#pragma unroll
            for (int r = 0; r < 4; ++r) {
                const int grow = grow0 + r;
                float sc2 = scale;
                if (ROWSCALE) sc2 = ((const float*)o3)[z * 1024 + grow];
                float v = acc[mi][ni][r] * sc2 + bb;
                const size_t growz = (size_t)grow;
                if (OUTM == 0) {
                    ((float*)o1 + z * sC)[growz * ldc + gcol] = v;
                } else if (OUTM == 1) {
                    if (gcol < 768) {
                        unsigned short h = bf16_rn(v);
                        ((unsigned short*)o1)[growz * 768 + gcol] = h;
                        ((unsigned short*)o2)[growz * 768 + gcol] = bf16_rn(v - bf16f(h));
                    } else if (gcol < 1536) {
                        int cc = gcol - 768;
                        unsigned short h = bf16_rn(v);
                        ((unsigned short*)o3)[growz * 768 + cc] = h;
                        ((unsigned short*)o4)[growz * 768 + cc] = bf16_rn(v - bf16f(h));
                    } else {
                        ((float*)o5)[growz * 768 + (gcol - 1536)] = v;
                    }
                } else {
                    unsigned short h = bf16_rn(v);
                    ((unsigned short*)o1 + z * sC)[growz * ldc + gcol] = h;
                    ((unsigned short*)o2 + z * sC)[growz * ldc + gcol] = bf16_rn(v - bf16f(h));
                }
            }
        }
    }

    if (OUTM == 0 && ROWMAX) {
        unsigned* mrow = (unsigned*)o2 + z * 1024;
#pragma unroll
        for (int mi = 0; mi < 8; ++mi) {
            const int grow0 = bm + wr * 128 + mi * 16 + ((lane >> 4) << 2);
#pragma unroll
            for (int r = 0; r < 4; ++r) {
                float mx = acc[mi][0][r];
#pragma unroll
                for (int ni = 1; ni < 4; ++ni) mx = fmaxf(mx, acc[mi][ni][r]);
                mx *= scale;   // scale > 0: max commutes
#pragma unroll
                for (int off = 1; off < 16; off <<= 1)
                    mx = fmaxf(mx, __shfl_xor(mx, off));
                if ((lane & 15) == 0) atomicMax(&mrow[grow0 + r], fenc(mx));
            }
        }
    }
}

// ==================== elementwise fp32 -> hi/lo bf16 split =================
__global__ __launch_bounds__(256)
void split_k(const float* __restrict__ src, unsigned short* __restrict__ dh,
             unsigned short* __restrict__ dl, long long n8)
{
    long long i = (long long)blockIdx.x * 256 + threadIdx.x;
    const long long stride = (long long)gridDim.x * 256;
    for (; i < n8; i += stride) {
        const float4* p = (const float4*)(src + i * 8);
        float4 f0 = p[0], f1 = p[1];
        float ff[8] = {f0.x, f0.y, f0.z, f0.w, f1.x, f1.y, f1.z, f1.w};
        bf16x8 hv, lv;
#pragma unroll
        for (int j = 0; j < 8; ++j) {
            unsigned short h = bf16_rn(ff[j]);
            hv[j] = (short)h;
            lv[j] = (short)bf16_rn(ff[j] - bf16f(h));
        }
        *(bf16x8*)(dh + i * 8) = hv;
        *(bf16x8*)(dl + i * 8) = lv;
    }
}

// ==================== transpose + split to hi/lo bf16 ======================
__global__ __launch_bounds__(256)
void tsplit_k(const float* __restrict__ src, unsigned short* __restrict__ dh,
              unsigned short* __restrict__ dl, int ls, long long ss,
              int ld_, long long sd)
{
    src += (long long)blockIdx.z * ss;
    dh  += (long long)blockIdx.z * sd;
    dl  += (long long)blockIdx.z * sd;
    __shared__ float t[32][33];
    const int tx = threadIdx.x & 31, ty = threadIdx.x >> 5;
    const int r0 = blockIdx.y * 32, c0 = blockIdx.x * 32;
#pragma unroll
    for (int i = 0; i < 4; ++i)
        t[ty + 8 * i][tx] = src[(size_t)(r0 + ty + 8 * i) * ls + c0 + tx];
    __syncthreads();
#pragma unroll
    for (int i = 0; i < 4; ++i) {
        float v = t[tx][ty + 8 * i];
        unsigned short h = bf16_rn(v);
        size_t o = (size_t)(c0 + ty + 8 * i) * ld_ + r0 + tx;
        dh[o] = h;
        dl[o] = bf16_rn(v - bf16f(h));
    }
}

// ==================== gw = softmax(V @ w_gp) -> hi/lo bf16, padded to 64 ===
__global__ __launch_bounds__(64)
void gw_k(const float* __restrict__ Vf, const float* __restrict__ wgp,
          unsigned short* __restrict__ gh, unsigned short* __restrict__ gl)
{
    const long long row = blockIdx.x;
    const int lane = threadIdx.x;
    const float* v = Vf + row * 768;
    float a0 = 0.f, a1 = 0.f, a2 = 0.f, a3 = 0.f;
    if (lane < 49) {
        for (int d = 0; d < 768; d += 4) {
            float4 vv = *(const float4*)&v[d];
            a0 = fmaf(vv.x, wgp[(d + 0) * 49 + lane], a0);
            a1 = fmaf(vv.y, wgp[(d + 1) * 49 + lane], a1);
            a2 = fmaf(vv.z, wgp[(d + 2) * 49 + lane], a2);
            a3 = fmaf(vv.w, wgp[(d + 3) * 49 + lane], a3);
        }
    }
    float logit = (lane < 49) ? ((a0 + a1) + (a2 + a3)) : -INFINITY;
    float m = logit;
    for (int off = 32; off; off >>= 1) m = fmaxf(m, __shfl_xor(m, off));
    float e = (lane < 49) ? expf(logit - m) : 0.f;
    float s = e;
    for (int off = 32; off; off >>= 1) s += __shfl_xor(s, off);
    float val = e / s;                       // 0 for pad lanes 49..63
    unsigned short h = bf16_rn(val);
    gh[row * 64 + lane] = h;
    gl[row * 64 + lane] = bf16_rn(val - bf16f(h));
}

// ==================== init m vector to encoded -inf ========================
__global__ __launch_bounds__(256)
void minit_k(unsigned* __restrict__ m, int n)
{
    int i = blockIdx.x * 256 + threadIdx.x;
    if (i < n) m[i] = 0x007FFFFFu;   // fenc(-inf)
}

// ==================== MFMA mod kernel ======================================
// w = exp(s-m)*G via MFMA (G = gw_q.gw_k, K=64 zero-padded), single pass
// over S; unscaled w as bf16 hi/lo; per-row f stored to fvec and applied
// in the attn@V epilogue. Block: 64 q-rows x 1024 k, 4 waves 2x2.
__global__ __launch_bounds__(256, 2)
void modm_k(const float* __restrict__ SC,
            const unsigned short* __restrict__ gwH, const unsigned short* __restrict__ gwL,
            const unsigned* __restrict__ menc,
            float* __restrict__ fvec,
            unsigned short* __restrict__ Sh, unsigned short* __restrict__ Sl)
{
    const int tid = threadIdx.x;
    const int qb  = blockIdx.x;              // 16 tiles of 64 rows
    const long long b = blockIdx.y;
    const int wv = tid >> 6, wr = wv >> 1, wc = wv & 1, lane = tid & 63;
    const int l15 = lane & 15, l4 = lane >> 4;

    const long long rowblk = b * 1024 + qb * 64;

    bf16x8 ah[2][2], al[2][2];
#pragma unroll
    for (int mi = 0; mi < 2; ++mi)
#pragma unroll
        for (int kt = 0; kt < 2; ++kt) {
            long long ga = (rowblk + wr * 32 + mi * 16 + l15) * 64 + kt * 32 + l4 * 8;
            ah[mi][kt] = *(const bf16x8*)&gwH[ga];
            al[mi][kt] = *(const bf16x8*)&gwL[ga];
        }

    float mval[8];
#pragma unroll
    for (int mi = 0; mi < 2; ++mi)
#pragma unroll
        for (int r = 0; r < 4; ++r) {
            long long row = rowblk + wr * 32 + mi * 16 + l4 * 4 + r;
            mval[mi * 4 + r] = fdec(menc[row]);
        }

    float Tp[8], Zp[8], Gp[8];
#pragma unroll
    for (int s = 0; s < 8; ++s) { Tp[s] = 0.f; Zp[s] = 0.f; Gp[s] = 0.f; }

    for (int kn = 0; kn < 8; ++kn) {
        bf16x8 bh[4][2], bl[4][2];
#pragma unroll
        for (int ni = 0; ni < 4; ++ni)
#pragma unroll
            for (int kt = 0; kt < 2; ++kt) {
                long long gb = (b * 1024 + kn * 128 + wc * 64 + ni * 16 + l15) * 64
                             + kt * 32 + l4 * 8;
                bh[ni][kt] = *(const bf16x8*)&gwH[gb];
                bl[ni][kt] = *(const bf16x8*)&gwL[gb];
            }
#pragma unroll
        for (int mi = 0; mi < 2; ++mi) {
            f32x4 acc[4];
#pragma unroll
            for (int ni = 0; ni < 4; ++ni) {
                f32x4 a = (f32x4){0.f, 0.f, 0.f, 0.f};
#pragma unroll
                for (int kt = 0; kt < 2; ++kt) {
                    a = __builtin_amdgcn_mfma_f32_16x16x32_bf16(ah[mi][kt], bh[ni][kt], a, 0, 0, 0);
                    a = __builtin_amdgcn_mfma_f32_16x16x32_bf16(ah[mi][kt], bl[ni][kt], a, 0, 0, 0);
                    a = __builtin_amdgcn_mfma_f32_16x16x32_bf16(al[mi][kt], bh[ni][kt], a, 0, 0, 0);
                }
                acc[ni] = a;
            }
#pragma unroll
            for (int ni = 0; ni < 4; ++ni) {
                const int col = kn * 128 + wc * 64 + ni * 16 + l15;
#pragma unroll
                for (int r = 0; r < 4; ++r) {
                    const long long row = rowblk + wr * 32 + mi * 16 + l4 * 4 + r;
                    float s = SC[row * 1024 + col];
                    float e = expf(s - mval[mi * 4 + r]);
                    float g = acc[ni][r];
                    float w = e * g;
                    Tp[mi * 4 + r] += w;
                    Zp[mi * 4 + r] += e;
                    Gp[mi * 4 + r] += g;
                    unsigned short h = bf16_rn(w);
                    Sh[row * 1024 + col] = h;
                    Sl[row * 1024 + col] = bf16_rn(w - bf16f(h));
                }
            }
        }
    }
#pragma unroll
    for (int s = 0; s < 8; ++s) {
#pragma unroll
        for (int off = 1; off < 16; off <<= 1) {
            Tp[s] += __shfl_xor(Tp[s], off);
            Zp[s] += __shfl_xor(Zp[s], off);
            Gp[s] += __shfl_xor(Gp[s], off);
        }
    }
    __shared__ float red[2][64][4];
    if (l15 == 0) {
#pragma unroll
        for (int mi = 0; mi < 2; ++mi)
#pragma unroll
            for (int r = 0; r < 4; ++r) {
                int rl = wr * 32 + mi * 16 + l4 * 4 + r;
                red[wc][rl][0] = Tp[mi * 4 + r];
                red[wc][rl][1] = Zp[mi * 4 + r];
                red[wc][rl][2] = Gp[mi * 4 + r];
            }
    }
    __syncthreads();
    if (tid < 64) {
        float T  = red[0][tid][0] + red[1][tid][0];
        float Z  = red[0][tid][1] + red[1][tid][1];
        float SG = red[0][tid][2] + red[1][tid][2];
        float c = 1024.f / (Z * (SG + 1e-8f));
        float f = c / (c * T + 1e-8f);
        fvec[rowblk + tid] = f;
    }
}

// ==================== launcher =============================================
extern "C" void kernel_launch(void* const* d_in, const int* in_sizes, int n_in,
                              void* d_out, int out_size, void* d_ws, size_t ws_size,
                              hipStream_t stream)
{
    const float* x      = (const float*)d_in[0];   // [32,1024,768]
    const float* w_qkv  = (const float*)d_in[1];   // [768,2304]
    const float* b_qkv  = (const float*)d_in[2];   // [2304]
    const float* w_proj = (const float*)d_in[3];   // [768,768]
    const float* b_proj = (const float*)d_in[4];   // [768]
    const float* w_gp   = (const float*)d_in[5];   // [768,49]
    float* out = (float*)d_out;

    auto need = [](int CB) -> size_t {
        size_t u = 0;
        u += 2ull * 2304 * 768;            // WqT h+l
        u += 2ull * 768 * 768;             // WpT h+l
        u += 4ull * CB * 1024 * 768;       // Qh,Ql,Kh,Kl (O aliases Q)
        u += 2ull * CB * 1024 * 768;       // VTh,VTl
        u += 2ull * CB * 1024 * 1024;      // Sh,Sl (aliased as Xh,Xl)
        u += 2ull * CB * 1024 * 64;        // gwH,gwL
        size_t bytes = u * 2;
        bytes += 4ull * ((size_t)CB * 1024 * 768      // Vf
                       + (size_t)CB * 1024 * 1024     // SC
                       + (size_t)CB * 1024            // fvec
                       + (size_t)CB * 1024);          // menc
        return bytes + 8192;
    };
    int CB = 32;
    while (CB > 1 && need(CB) > ws_size) CB >>= 1;
    const int MC = CB * 1024;

    char* cur = (char*)d_ws;
    auto alloc_u = [&](size_t n) {
        unsigned short* p = (unsigned short*)cur;
        cur += ((n * 2 + 15) & ~15ull);
        return p;
    };
    auto alloc_f = [&](size_t n) {
        float* p = (float*)cur;
        cur += ((n * 4 + 15) & ~15ull);
        return p;
    };
    unsigned short* WqTh = alloc_u(2304ull * 768);
    unsigned short* WqTl = alloc_u(2304ull * 768);
    unsigned short* WpTh = alloc_u(768ull * 768);
    unsigned short* WpTl = alloc_u(768ull * 768);
    unsigned short* Qh   = alloc_u((size_t)MC * 768);
    unsigned short* Ql   = alloc_u((size_t)MC * 768);
    unsigned short* Kh   = alloc_u((size_t)MC * 768);
    unsigned short* Kl   = alloc_u((size_t)MC * 768);
    unsigned short* VTh  = alloc_u((size_t)MC * 768);
    unsigned short* VTl  = alloc_u((size_t)MC * 768);
    unsigned short* Sh   = alloc_u((size_t)MC * 1024);
    unsigned short* Sl   = alloc_u((size_t)MC * 1024);
    unsigned short* gwH  = alloc_u((size_t)MC * 64);
    unsigned short* gwL  = alloc_u((size_t)MC * 64);
    float* Vf   = alloc_f((size_t)MC * 768);
    float* SC   = alloc_f((size_t)MC * 1024);
    float* fvec = alloc_f((size_t)MC);
    unsigned* menc = (unsigned*)alloc_f((size_t)MC);
    unsigned short* Oh = Qh;   // O aliases Q (Q dead after S=QK^T)
    unsigned short* Ol = Ql;
    unsigned short* Xh = Sh;   // x split aliases S (dead after step 1)
    unsigned short* Xl = Sl;

    const float scale = 1.0f / sqrtf(768.0f);

    // ---- weight prep (once per launch) ----
    tsplit_k<<<dim3(72, 24, 1), 256, 0, stream>>>(w_qkv, WqTh, WqTl, 2304, 0, 768, 0);
    tsplit_k<<<dim3(24, 24, 1), 256, 0, stream>>>(w_proj, WpTh, WpTl, 768, 0, 768, 0);

    for (int c = 0; c < 32 / CB; ++c) {
        const float* xc   = x   + (size_t)c * MC * 768;
        float*       outc = out + (size_t)c * MC * 768;

        // 0) split x -> hi/lo bf16
        {
            const long long n8 = (long long)MC * 768 / 8;
            int nb = (int)((n8 + 255) / 256);
            if (nb > 4096) nb = 4096;
            split_k<<<dim3(nb), 256, 0, stream>>>(xc, Xh, Xl, n8);
        }

        // 1) qkv GEMM: A = Xh/Xl, B = WqT -> Qh/Ql, Kh/Kl, Vf   (N=2304)
        mgemm<1, true, false, false><<<dim3(9, MC / 256, 1), 512, 0, stream>>>(
            Xh, Xl, WqTh, WqTl, b_qkv,
            Qh, Ql, Kh, Kl, Vf, 768, 768, 0, 0, 0, 0, 1.0f);

        // 2) gw = softmax(V @ w_gp) -> hi/lo bf16 padded to 64
        gw_k<<<dim3(MC), 64, 0, stream>>>(Vf, w_gp, gwH, gwL);

        // 3) V^T hi/lo per batch
        tsplit_k<<<dim3(24, 32, CB), 256, 0, stream>>>(
            Vf, VTh, VTl, 768, 1024ll * 768, 1024, 768ll * 1024);

        // 3b) init row-max vector
        minit_k<<<dim3((MC + 255) / 256), 256, 0, stream>>>(menc, MC);

        // 4) S = Q @ K^T * scale (per batch), epilogue row-max -> menc
        mgemm<0, false, true, false><<<dim3(4, 4, CB), 512, 0, stream>>>(
            Qh, Ql, Kh, Kl, nullptr,
            SC, menc, nullptr, nullptr, nullptr,
            768, 768, 1024, 1024ll * 768, 1024ll * 768, 1024ll * 1024, scale);

        // 5) w = exp(s-m)*G via MFMA -> Sh/Sl (unscaled); f per row -> fvec
        modm_k<<<dim3(16, CB), 256, 0, stream>>>(SC, gwH, gwL, menc, fvec, Sh, Sl);

        // 6) O = (w @ V) * f (per batch, row-scaled epilogue) -> Oh/Ol
        mgemm<2, false, false, true><<<dim3(3, 4, CB), 512, 0, stream>>>(
            Sh, Sl, VTh, VTl, nullptr,
            Oh, Ol, fvec, nullptr, nullptr,
            1024, 1024, 768, 1024ll * 1024, 768ll * 1024, 1024ll * 768, 1.0f);

        // 7) out = O @ w_proj + b_proj
        mgemm<0, true, false, false><<<dim3(3, MC / 256, 1), 512, 0, stream>>>(
            Oh, Ol, WpTh, WpTl, b_proj,
            outc, nullptr, nullptr, nullptr, nullptr,
            768, 768, 768, 0, 0, 0, 1.0f);
    }
}

// Round 8
// 1530.563 us; speedup vs baseline: 1.0540x; 1.0540x over previous
//
#include <hip/hip_runtime.h>
#include <math.h>

typedef short  bf16x8 __attribute__((ext_vector_type(8)));
typedef float  f32x4  __attribute__((ext_vector_type(4)));

__device__ __forceinline__ unsigned short bf16_rn(float x) {
    unsigned u = __float_as_uint(x);
    u += 0x7fffu + ((u >> 16) & 1u);
    return (unsigned short)(u >> 16);
}
__device__ __forceinline__ float bf16f(unsigned short h) {
    return __uint_as_float(((unsigned)h) << 16);
}

// async global->LDS, 16B per lane. HW writes LDS at wave-uniform base + lane*16
// (m104/m108); per-lane GLOBAL address carries the layout permutation (m173).
__device__ __forceinline__ void gl2lds16(const void* gptr, void* lptr) {
    __builtin_amdgcn_global_load_lds(
        (const __attribute__((address_space(1))) unsigned int*)(unsigned long long)gptr,
        (__attribute__((address_space(3))) unsigned int*)(unsigned int)(unsigned long long)lptr,
        16, 0, 0);
}

// ==================== MFMA split-bf16 GEMM (R6-verified core) ==============
// C = scale*(A@B) [+ bias], computed as Ah*Bh + Ah*Bl + Al*Bh on bf16 MFMA.
// Block tile 128x256, 512 threads = 8 waves (2 x 4), wave tile 64x64
// (4x4 of 16x16x32), BK=32. TRIPLE-buffered LDS (144 KB, 1 block/CU):
// restage target at kt is buf[(kt+2)%3] whose readers drained at kt-1 ->
// ONE barrier per K-step; counted vmcnt(6), vmcnt(0) only at tail; setprio
// around the MFMA cluster. This exact core measured 243us on the S-GEMM
// (R6, best). R7's 128x64 wave tile regressed (dep-chain stalls) - reverted.
// LDS per array: [blk][kg 4][row 16][8 bf16]; A 8 blks, B 16 blks.
// OUTM: 0 = fp32 C (o1)    1 = qkv epilogue (o1..o5 = Qh,Ql,Kh,Kl,Vfp32)
//       2 = hi/lo bf16 (o1,o2)
// ROWSCALE (OUTM=2): per-row scale from (const float*)o3 [z*1024+row].
template<int OUTM, bool HAS_BIAS, bool ROWSCALE>
__global__ __launch_bounds__(512, 2)
void mgemm(const unsigned short* __restrict__ Ah_, const unsigned short* __restrict__ Al_,
           const unsigned short* __restrict__ Bh_, const unsigned short* __restrict__ Bl_,
           const float* __restrict__ bias,
           void* o1, void* o2, void* o3, void* o4, void* o5,
           int K, int lda, int ldc,
           long long sA, long long sB, long long sC, float scale)
{
    const int tid = threadIdx.x;
    const int bm = blockIdx.y * 128;
    const int bn = blockIdx.x * 256;
    const long long z = blockIdx.z;

    const unsigned short* Ahu = Ah_ + z * sA;
    const unsigned short* Alu = Al_ + z * sA;
    const unsigned short* Bhu = Bh_ + z * sB;
    const unsigned short* Blu = Bl_ + z * sB;

    __shared__ unsigned short LA_h[3][4096], LA_l[3][4096];   // 8 blks x 512
    __shared__ unsigned short LB_h[3][8192], LB_l[3][8192];   // 16 blks x 512

    const int wv = tid >> 6, lane = tid & 63;
    const int wr = wv >> 2, wc = wv & 3;                  // 2 x 4 wave grid
    const int fro = (lane >> 4) * 128 + (lane & 15) * 8;  // frag offset in blk

    const int srow = lane & 15, skg = lane >> 4;
    const size_t gaA  = (size_t)(bm + 16 * wv + srow) * lda + skg * 8;
    const size_t gaB0 = (size_t)(bn + 32 * wv + srow) * lda + skg * 8;
    const size_t gaB1 = (size_t)(bn + 32 * wv + 16 + srow) * lda + skg * 8;
    const int loA = wv * 512, loB = wv * 1024;

    auto stage = [&](int bb, int k0) {   // 6 x global_load_lds_dwordx4 / wave
        gl2lds16(&Ahu[gaA  + k0], &LA_h[bb][loA]);
        gl2lds16(&Alu[gaA  + k0], &LA_l[bb][loA]);
        gl2lds16(&Bhu[gaB0 + k0], &LB_h[bb][loB]);
        gl2lds16(&Bhu[gaB1 + k0], &LB_h[bb][loB + 512]);
        gl2lds16(&Blu[gaB0 + k0], &LB_l[bb][loB]);
        gl2lds16(&Blu[gaB1 + k0], &LB_l[bb][loB + 512]);
    };

    f32x4 acc[4][4];
#pragma unroll
    for (int i = 0; i < 4; ++i)
#pragma unroll
        for (int j = 0; j < 4; ++j) acc[i][j] = (f32x4){0.f, 0.f, 0.f, 0.f};

    const int nkt = K >> 5;      // >= 24 at all call sites
    stage(0, 0);
    stage(1, 32);
    for (int kt = 0; kt < nkt; ++kt) {
        const int cb = kt % 3;
        if (kt < nkt - 1) {
            asm volatile("s_waitcnt vmcnt(6)" ::: "memory");
        } else {
            asm volatile("s_waitcnt vmcnt(0)" ::: "memory");
        }
        __builtin_amdgcn_sched_barrier(0);
        __builtin_amdgcn_s_barrier();            // buf[cb] landed;
        __builtin_amdgcn_sched_barrier(0);       // buf[(kt+2)%3] fully drained

        if (kt + 2 < nkt) stage((kt + 2) % 3, (kt + 2) << 5);

        bf16x8 bhf[4], blf[4], ahf[4], alf[4];
#pragma unroll
        for (int ni = 0; ni < 4; ++ni) {
            int off = (wc * 4 + ni) * 512 + fro;
            bhf[ni] = *(const bf16x8*)&LB_h[cb][off];
            blf[ni] = *(const bf16x8*)&LB_l[cb][off];
        }
#pragma unroll
        for (int mi = 0; mi < 4; ++mi) {
            int off = (wr * 4 + mi) * 512 + fro;
            ahf[mi] = *(const bf16x8*)&LA_h[cb][off];
            alf[mi] = *(const bf16x8*)&LA_l[cb][off];
        }
        asm volatile("s_waitcnt lgkmcnt(0)" ::: "memory");
        __builtin_amdgcn_sched_barrier(0);

        __builtin_amdgcn_s_setprio(1);
#pragma unroll
        for (int mi = 0; mi < 4; ++mi) {
#pragma unroll
            for (int ni = 0; ni < 4; ++ni) {
                f32x4 a = acc[mi][ni];
                a = __builtin_amdgcn_mfma_f32_16x16x32_bf16(ahf[mi], bhf[ni], a, 0, 0, 0);
                a = __builtin_amdgcn_mfma_f32_16x16x32_bf16(ahf[mi], blf[ni], a, 0, 0, 0);
                a = __builtin_amdgcn_mfma_f32_16x16x32_bf16(alf[mi], bhf[ni], a, 0, 0, 0);
                acc[mi][ni] = a;
            }
        }
        __builtin_amdgcn_s_setprio(0);
    }

    // ---- epilogue: C/D layout col=lane&15, row=(lane>>4)*4+r ----
#pragma unroll
    for (int mi = 0; mi < 4; ++mi) {
#pragma unroll
        for (int ni = 0; ni < 4; ++ni) {
            const int grow0 = bm + wr * 64 + mi * 16 + ((lane >> 4) << 2);
            const int gcol  = bn + wc * 64 + ni * 16 + (lane & 15);
            float bb = HAS_BIAS ? bias[gcol] : 0.f;
#pragma unroll
            for (int r = 0; r < 4; ++r) {
                const int grow = grow0 + r;
                float sc2 = scale;
                if (ROWSCALE) sc2 = ((const float*)o3)[z * 1024 + grow];
                float v = acc[mi][ni][r] * sc2 + bb;
                const size_t growz = (size_t)grow;
                if (OUTM == 0) {
                    ((float*)o1 + z * sC)[growz * ldc + gcol] = v;
                } else if (OUTM == 1) {
                    if (gcol < 768) {
                        unsigned short h = bf16_rn(v);
                        ((unsigned short*)o1)[growz * 768 + gcol] = h;
                        ((unsigned short*)o2)[growz * 768 + gcol] = bf16_rn(v - bf16f(h));
                    } else if (gcol < 1536) {
                        int cc = gcol - 768;
                        unsigned short h = bf16_rn(v);
                        ((unsigned short*)o3)[growz * 768 + cc] = h;
                        ((unsigned short*)o4)[growz * 768 + cc] = bf16_rn(v - bf16f(h));
                    } else {
                        ((float*)o5)[growz * 768 + (gcol - 1536)] = v;
                    }
                } else {
                    unsigned short h = bf16_rn(v);
                    ((unsigned short*)o1 + z * sC)[growz * ldc + gcol] = h;
                    ((unsigned short*)o2 + z * sC)[growz * ldc + gcol] = bf16_rn(v - bf16f(h));
                }
            }
        }
    }
}

// ==================== fused S + G + modulation kernel ======================
// smod: S-tile = Q@K^T (R6 K-loop core verbatim), then G = gw_q.gw_k via
// MFMA (K=64 zero-padded, frags straight from global/L2, +8% MFMA), then
// w = exp(s*scale)*g written as bf16 hi/lo; per-row T=Σw, Z=Σe, SG=Σg
// atomicAdd'd to Tv/Zv/Gv. KEY: m (row max) is mathematically arbitrary --
// attn = w*c/(cT+eps), c = n/(Z(SG+eps)) is EXACTLY m-invariant (e,T,Z scale
// e^-Δ; c,f scale e^+Δ; both eps terms attach to m-invariant quantities).
// |s| <= ||q||*||k||/sqrt(d) ~ 28 << 88 (expf overflow) -> m=0 is safe and
// the rowmax pre-pass + modm kernel + SC fp32 round-trip all disappear.
__global__ __launch_bounds__(512, 2)
void smod(const unsigned short* __restrict__ Ah_, const unsigned short* __restrict__ Al_,
          const unsigned short* __restrict__ Bh_, const unsigned short* __restrict__ Bl_,
          const unsigned short* __restrict__ gwH, const unsigned short* __restrict__ gwL,
          unsigned short* __restrict__ Sh, unsigned short* __restrict__ Sl,
          float* __restrict__ Tv, float* __restrict__ Zv, float* __restrict__ Gv,
          float scale)
{
    const int tid = threadIdx.x;
    const int bm = blockIdx.y * 128;
    const int bn = blockIdx.x * 256;
    const long long z = blockIdx.z;
    const int lda = 768;

    const unsigned short* Ahu = Ah_ + z * 1024ll * 768;
    const unsigned short* Alu = Al_ + z * 1024ll * 768;
    const unsigned short* Bhu = Bh_ + z * 1024ll * 768;
    const unsigned short* Blu = Bl_ + z * 1024ll * 768;

    __shared__ unsigned short LA_h[3][4096], LA_l[3][4096];
    __shared__ unsigned short LB_h[3][8192], LB_l[3][8192];

    const int wv = tid >> 6, lane = tid & 63;
    const int wr = wv >> 2, wc = wv & 3;
    const int fro = (lane >> 4) * 128 + (lane & 15) * 8;
    const int l15 = lane & 15, l4 = lane >> 4;

    const size_t gaA  = (size_t)(bm + 16 * wv + l15) * lda + l4 * 8;
    const size_t gaB0 = (size_t)(bn + 32 * wv + l15) * lda + l4 * 8;
    const size_t gaB1 = (size_t)(bn + 32 * wv + 16 + l15) * lda + l4 * 8;
    const int loA = wv * 512, loB = wv * 1024;

    auto stage = [&](int bb, int k0) {
        gl2lds16(&Ahu[gaA  + k0], &LA_h[bb][loA]);
        gl2lds16(&Alu[gaA  + k0], &LA_l[bb][loA]);
        gl2lds16(&Bhu[gaB0 + k0], &LB_h[bb][loB]);
        gl2lds16(&Bhu[gaB1 + k0], &LB_h[bb][loB + 512]);
        gl2lds16(&Blu[gaB0 + k0], &LB_l[bb][loB]);
        gl2lds16(&Blu[gaB1 + k0], &LB_l[bb][loB + 512]);
    };

    f32x4 acc[4][4];
#pragma unroll
    for (int i = 0; i < 4; ++i)
#pragma unroll
        for (int j = 0; j < 4; ++j) acc[i][j] = (f32x4){0.f, 0.f, 0.f, 0.f};

    const int nkt = 768 >> 5;    // 24
    stage(0, 0);
    stage(1, 32);
    for (int kt = 0; kt < nkt; ++kt) {
        const int cb = kt % 3;
        if (kt < nkt - 1) {
            asm volatile("s_waitcnt vmcnt(6)" ::: "memory");
        } else {
            asm volatile("s_waitcnt vmcnt(0)" ::: "memory");
        }
        __builtin_amdgcn_sched_barrier(0);
        __builtin_amdgcn_s_barrier();
        __builtin_amdgcn_sched_barrier(0);

        if (kt + 2 < nkt) stage((kt + 2) % 3, (kt + 2) << 5);

        bf16x8 bhf[4], blf[4], ahf[4], alf[4];
#pragma unroll
        for (int ni = 0; ni < 4; ++ni) {
            int off = (wc * 4 + ni) * 512 + fro;
            bhf[ni] = *(const bf16x8*)&LB_h[cb][off];
            blf[ni] = *(const bf16x8*)&LB_l[cb][off];
        }
#pragma unroll
        for (int mi = 0; mi < 4; ++mi) {
            int off = (wr * 4 + mi) * 512 + fro;
            ahf[mi] = *(const bf16x8*)&LA_h[cb][off];
            alf[mi] = *(const bf16x8*)&LA_l[cb][off];
        }
        asm volatile("s_waitcnt lgkmcnt(0)" ::: "memory");
        __builtin_amdgcn_sched_barrier(0);

        __builtin_amdgcn_s_setprio(1);
#pragma unroll
        for (int mi = 0; mi < 4; ++mi) {
#pragma unroll
            for (int ni = 0; ni < 4; ++ni) {
                f32x4 a = acc[mi][ni];
                a = __builtin_amdgcn_mfma_f32_16x16x32_bf16(ahf[mi], bhf[ni], a, 0, 0, 0);
                a = __builtin_amdgcn_mfma_f32_16x16x32_bf16(ahf[mi], blf[ni], a, 0, 0, 0);
                a = __builtin_amdgcn_mfma_f32_16x16x32_bf16(alf[mi], bhf[ni], a, 0, 0, 0);
                acc[mi][ni] = a;
            }
        }
        __builtin_amdgcn_s_setprio(0);
    }

    // ---- fused epilogue: G via MFMA + w = exp(s*scale)*g ----
    // G-acc has the SAME C/D layout as S-acc (same MFMA shape), so the
    // elementwise combine is per-register. B-frags re-read per mi (L1/L2 hot)
    // to cap register pressure.
    const long long gwz = z * 1024 * 64;
    float Tp[16], Zp[16], Gp[16];
#pragma unroll
    for (int s = 0; s < 16; ++s) { Tp[s] = 0.f; Zp[s] = 0.f; Gp[s] = 0.f; }

    unsigned short* ShZ = Sh + z * 1024ll * 1024;
    unsigned short* SlZ = Sl + z * 1024ll * 1024;

#pragma unroll
    for (int mi = 0; mi < 4; ++mi) {
        bf16x8 gah[2], gal[2];
#pragma unroll
        for (int kt = 0; kt < 2; ++kt) {
            long long ga = gwz + (long long)(bm + wr * 64 + mi * 16 + l15) * 64
                         + kt * 32 + l4 * 8;
            gah[kt] = *(const bf16x8*)&gwH[ga];
            gal[kt] = *(const bf16x8*)&gwL[ga];
        }
#pragma unroll
        for (int ni = 0; ni < 4; ++ni) {
            bf16x8 gbh[2], gbl[2];
#pragma unroll
            for (int kt = 0; kt < 2; ++kt) {
                long long gb = gwz + (long long)(bn + wc * 64 + ni * 16 + l15) * 64
                             + kt * 32 + l4 * 8;
                gbh[kt] = *(const bf16x8*)&gwH[gb];
                gbl[kt] = *(const bf16x8*)&gwL[gb];
            }
            f32x4 g4 = (f32x4){0.f, 0.f, 0.f, 0.f};
#pragma unroll
            for (int kt = 0; kt < 2; ++kt) {
                g4 = __builtin_amdgcn_mfma_f32_16x16x32_bf16(gah[kt], gbh[kt], g4, 0, 0, 0);
                g4 = __builtin_amdgcn_mfma_f32_16x16x32_bf16(gah[kt], gbl[kt], g4, 0, 0, 0);
                g4 = __builtin_amdgcn_mfma_f32_16x16x32_bf16(gal[kt], gbh[kt], g4, 0, 0, 0);
            }
            const int col = bn + wc * 64 + ni * 16 + l15;
#pragma unroll
            for (int r = 0; r < 4; ++r) {
                const int row = bm + wr * 64 + mi * 16 + l4 * 4 + r;
                float e = expf(acc[mi][ni][r] * scale);   // m = 0 (invariant)
                float g = g4[r];
                float w = e * g;
                Tp[mi * 4 + r] += w;
                Zp[mi * 4 + r] += e;
                Gp[mi * 4 + r] += g;
                unsigned short h = bf16_rn(w);
                ShZ[(size_t)row * 1024 + col] = h;
                SlZ[(size_t)row * 1024 + col] = bf16_rn(w - bf16f(h));
            }
        }
    }
    // reduce over the 16 lanes sharing each row (lane bits 0-3 = cols)
#pragma unroll
    for (int s = 0; s < 16; ++s) {
#pragma unroll
        for (int off = 1; off < 16; off <<= 1) {
            Tp[s] += __shfl_xor(Tp[s], off);
            Zp[s] += __shfl_xor(Zp[s], off);
            Gp[s] += __shfl_xor(Gp[s], off);
        }
    }
    if (l15 == 0) {
        float* TvZ = Tv + z * 1024;
        float* ZvZ = Zv + z * 1024;
        float* GvZ = Gv + z * 1024;
#pragma unroll
        for (int mi = 0; mi < 4; ++mi)
#pragma unroll
            for (int r = 0; r < 4; ++r) {
                const int row = bm + wr * 64 + mi * 16 + l4 * 4 + r;
                atomicAdd(&TvZ[row], Tp[mi * 4 + r]);
                atomicAdd(&ZvZ[row], Zp[mi * 4 + r]);
                atomicAdd(&GvZ[row], Gp[mi * 4 + r]);
            }
    }
}

// ==================== elementwise fp32 -> hi/lo bf16 split =================
__global__ __launch_bounds__(256)
void split_k(const float* __restrict__ src, unsigned short* __restrict__ dh,
             unsigned short* __restrict__ dl, long long n8)
{
    long long i = (long long)blockIdx.x * 256 + threadIdx.x;
    const long long stride = (long long)gridDim.x * 256;
    for (; i < n8; i += stride) {
        const float4* p = (const float4*)(src + i * 8);
        float4 f0 = p[0], f1 = p[1];
        float ff[8] = {f0.x, f0.y, f0.z, f0.w, f1.x, f1.y, f1.z, f1.w};
        bf16x8 hv, lv;
#pragma unroll
        for (int j = 0; j < 8; ++j) {
            unsigned short h = bf16_rn(ff[j]);
            hv[j] = (short)h;
            lv[j] = (short)bf16_rn(ff[j] - bf16f(h));
        }
        *(bf16x8*)(dh + i * 8) = hv;
        *(bf16x8*)(dl + i * 8) = lv;
    }
}

// ==================== transpose + split to hi/lo bf16 ======================
__global__ __launch_bounds__(256)
void tsplit_k(const float* __restrict__ src, unsigned short* __restrict__ dh,
              unsigned short* __restrict__ dl, int ls, long long ss,
              int ld_, long long sd)
{
    src += (long long)blockIdx.z * ss;
    dh  += (long long)blockIdx.z * sd;
    dl  += (long long)blockIdx.z * sd;
    __shared__ float t[32][33];
    const int tx = threadIdx.x & 31, ty = threadIdx.x >> 5;
    const int r0 = blockIdx.y * 32, c0 = blockIdx.x * 32;
#pragma unroll
    for (int i = 0; i < 4; ++i)
        t[ty + 8 * i][tx] = src[(size_t)(r0 + ty + 8 * i) * ls + c0 + tx];
    __syncthreads();
#pragma unroll
    for (int i = 0; i < 4; ++i) {
        float v = t[tx][ty + 8 * i];
        unsigned short h = bf16_rn(v);
        size_t o = (size_t)(c0 + ty + 8 * i) * ld_ + r0 + tx;
        dh[o] = h;
        dl[o] = bf16_rn(v - bf16f(h));
    }
}

// ==================== gw = softmax(V @ w_gp) -> hi/lo bf16, padded to 64 ===
__global__ __launch_bounds__(64)
void gw_k(const float* __restrict__ Vf, const float* __restrict__ wgp,
          unsigned short* __restrict__ gh, unsigned short* __restrict__ gl)
{
    const long long row = blockIdx.x;
    const int lane = threadIdx.x;
    const float* v = Vf + row * 768;
    float a0 = 0.f, a1 = 0.f, a2 = 0.f, a3 = 0.f;
    if (lane < 49) {
        for (int d = 0; d < 768; d += 4) {
            float4 vv = *(const float4*)&v[d];
            a0 = fmaf(vv.x, wgp[(d + 0) * 49 + lane], a0);
            a1 = fmaf(vv.y, wgp[(d + 1) * 49 + lane], a1);
            a2 = fmaf(vv.z, wgp[(d + 2) * 49 + lane], a2);
            a3 = fmaf(vv.w, wgp[(d + 3) * 49 + lane], a3);
        }
    }
    float logit = (lane < 49) ? ((a0 + a1) + (a2 + a3)) : -INFINITY;
    float m = logit;
    for (int off = 32; off; off >>= 1) m = fmaxf(m, __shfl_xor(m, off));
    float e = (lane < 49) ? expf(logit - m) : 0.f;
    float s = e;
    for (int off = 32; off; off >>= 1) s += __shfl_xor(s, off);
    float val = e / s;                       // 0 for pad lanes 49..63
    unsigned short h = bf16_rn(val);
    gh[row * 64 + lane] = h;
    gl[row * 64 + lane] = bf16_rn(val - bf16f(h));
}

// ==================== zero-init for T/Z/SG accumulators ====================
__global__ __launch_bounds__(256)
void zinit_k(float* __restrict__ p, int n)
{
    int i = blockIdx.x * 256 + threadIdx.x;
    if (i < n) p[i] = 0.f;
}

// ==================== f = c/(cT+eps), c = n/(Z(SG+eps)) ====================
__global__ __launch_bounds__(256)
void fcomp_k(const float* __restrict__ Tv, const float* __restrict__ Zv,
             const float* __restrict__ Gv, float* __restrict__ fvec, int n)
{
    int i = blockIdx.x * 256 + threadIdx.x;
    if (i < n) {
        float c = 1024.f / (Zv[i] * (Gv[i] + 1e-8f));
        fvec[i] = c / (c * Tv[i] + 1e-8f);
    }
}

// ==================== launcher =============================================
extern "C" void kernel_launch(void* const* d_in, const int* in_sizes, int n_in,
                              void* d_out, int out_size, void* d_ws, size_t ws_size,
                              hipStream_t stream)
{
    const float* x      = (const float*)d_in[0];   // [32,1024,768]
    const float* w_qkv  = (const float*)d_in[1];   // [768,2304]
    const float* b_qkv  = (const float*)d_in[2];   // [2304]
    const float* w_proj = (const float*)d_in[3];   // [768,768]
    const float* b_proj = (const float*)d_in[4];   // [768]
    const float* w_gp   = (const float*)d_in[5];   // [768,49]
    float* out = (float*)d_out;

    auto need = [](int CB) -> size_t {
        size_t u = 0;
        u += 2ull * 2304 * 768;            // WqT h+l
        u += 2ull * 768 * 768;             // WpT h+l
        u += 4ull * CB * 1024 * 768;       // Qh,Ql,Kh,Kl (O aliases Q)
        u += 2ull * CB * 1024 * 768;       // VTh,VTl
        u += 2ull * CB * 1024 * 1024;      // Sh,Sl (aliased as Xh,Xl)
        u += 2ull * CB * 1024 * 64;        // gwH,gwL
        size_t bytes = u * 2;
        bytes += 4ull * ((size_t)CB * 1024 * 768      // Vf
                       + 5ull * CB * 1024);           // Tv,Zv,Gv,fvec + pad
        return bytes + 8192;
    };
    int CB = 32;
    while (CB > 1 && need(CB) > ws_size) CB >>= 1;
    const int MC = CB * 1024;

    char* cur = (char*)d_ws;
    auto alloc_u = [&](size_t n) {
        unsigned short* p = (unsigned short*)cur;
        cur += ((n * 2 + 15) & ~15ull);
        return p;
    };
    auto alloc_f = [&](size_t n) {
        float* p = (float*)cur;
        cur += ((n * 4 + 15) & ~15ull);
        return p;
    };
    unsigned short* WqTh = alloc_u(2304ull * 768);
    unsigned short* WqTl = alloc_u(2304ull * 768);
    unsigned short* WpTh = alloc_u(768ull * 768);
    unsigned short* WpTl = alloc_u(768ull * 768);
    unsigned short* Qh   = alloc_u((size_t)MC * 768);
    unsigned short* Ql   = alloc_u((size_t)MC * 768);
    unsigned short* Kh   = alloc_u((size_t)MC * 768);
    unsigned short* Kl   = alloc_u((size_t)MC * 768);
    unsigned short* VTh  = alloc_u((size_t)MC * 768);
    unsigned short* VTl  = alloc_u((size_t)MC * 768);
    unsigned short* Sh   = alloc_u((size_t)MC * 1024);
    unsigned short* Sl   = alloc_u((size_t)MC * 1024);
    unsigned short* gwH  = alloc_u((size_t)MC * 64);
    unsigned short* gwL  = alloc_u((size_t)MC * 64);
    float* Vf   = alloc_f((size_t)MC * 768);
    float* Tv   = alloc_f((size_t)MC);
    float* Zv   = alloc_f((size_t)MC);
    float* Gv   = alloc_f((size_t)MC);
    float* fvec = alloc_f((size_t)MC);
    unsigned short* Oh = Qh;   // O aliases Q (Q dead after S=QK^T)
    unsigned short* Ol = Ql;
    unsigned short* Xh = Sh;   // x split aliases S (dead after step 1)
    unsigned short* Xl = Sl;

    const float scale = 1.0f / sqrtf(768.0f);

    // ---- weight prep (once per launch) ----
    tsplit_k<<<dim3(72, 24, 1), 256, 0, stream>>>(w_qkv, WqTh, WqTl, 2304, 0, 768, 0);
    tsplit_k<<<dim3(24, 24, 1), 256, 0, stream>>>(w_proj, WpTh, WpTl, 768, 0, 768, 0);

    for (int c = 0; c < 32 / CB; ++c) {
        const float* xc   = x   + (size_t)c * MC * 768;
        float*       outc = out + (size_t)c * MC * 768;

        // 0) split x -> hi/lo bf16
        {
            const long long n8 = (long long)MC * 768 / 8;
            int nb = (int)((n8 + 255) / 256);
            if (nb > 4096) nb = 4096;
            split_k<<<dim3(nb), 256, 0, stream>>>(xc, Xh, Xl, n8);
        }

        // 1) qkv GEMM: A = Xh/Xl, B = WqT -> Qh/Ql, Kh/Kl, Vf   (N=2304)
        mgemm<1, true, false><<<dim3(9, MC / 128, 1), 512, 0, stream>>>(
            Xh, Xl, WqTh, WqTl, b_qkv,
            Qh, Ql, Kh, Kl, Vf, 768, 768, 0, 0, 0, 0, 1.0f);

        // 2) gw = softmax(V @ w_gp) -> hi/lo bf16 padded to 64
        gw_k<<<dim3(MC), 64, 0, stream>>>(Vf, w_gp, gwH, gwL);

        // 3) V^T hi/lo per batch
        tsplit_k<<<dim3(24, 32, CB), 256, 0, stream>>>(
            Vf, VTh, VTl, 768, 1024ll * 768, 1024, 768ll * 1024);

        // 3b) zero T/Z/SG accumulators (contiguous: Tv,Zv,Gv)
        zinit_k<<<dim3((3 * MC + 255) / 256), 256, 0, stream>>>(Tv, 3 * MC);

        // 4) fused S=QK^T + G + w=exp(s)*g -> Sh/Sl; T/Z/SG atomics
        smod<<<dim3(4, 8, CB), 512, 0, stream>>>(
            Qh, Ql, Kh, Kl, gwH, gwL, Sh, Sl, Tv, Zv, Gv, scale);

        // 5) f per row from T/Z/SG
        fcomp_k<<<dim3((MC + 255) / 256), 256, 0, stream>>>(Tv, Zv, Gv, fvec, MC);

        // 6) O = (w @ V) * f (per batch, row-scaled epilogue) -> Oh/Ol
        mgemm<2, false, true><<<dim3(3, 8, CB), 512, 0, stream>>>(
            Sh, Sl, VTh, VTl, nullptr,
            Oh, Ol, fvec, nullptr, nullptr,
            1024, 1024, 768, 1024ll * 1024, 768ll * 1024, 1024ll * 768, 1.0f);

        // 7) out = O @ w_proj + b_proj
        mgemm<0, true, false><<<dim3(3, MC / 128, 1), 512, 0, stream>>>(
            Oh, Ol, WpTh, WpTl, b_proj,
            outc, nullptr, nullptr, nullptr, nullptr,
            768, 768, 768, 0, 0, 0, 1.0f);
    }
}

// Round 9
// 1526.535 us; speedup vs baseline: 1.0567x; 1.0026x over previous
//
#include <hip/hip_runtime.h>
#include <math.h>

typedef short  bf16x8 __attribute__((ext_vector_type(8)));
typedef float  f32x4  __attribute__((ext_vector_type(4)));

__device__ __forceinline__ unsigned short bf16_rn(float x) {
    unsigned u = __float_as_uint(x);
    u += 0x7fffu + ((u >> 16) & 1u);
    return (unsigned short)(u >> 16);
}
__device__ __forceinline__ float bf16f(unsigned short h) {
    return __uint_as_float(((unsigned)h) << 16);
}

// async global->LDS, 16B per lane. HW writes LDS at wave-uniform base + lane*16
// (m104/m108); per-lane GLOBAL address carries the layout permutation (m173).
__device__ __forceinline__ void gl2lds16(const void* gptr, void* lptr) {
    __builtin_amdgcn_global_load_lds(
        (const __attribute__((address_space(1))) unsigned int*)(unsigned long long)gptr,
        (__attribute__((address_space(3))) unsigned int*)(unsigned int)(unsigned long long)lptr,
        16, 0, 0);
}

// ==================== MFMA split-bf16 GEMM (R6 core, fence removed) ========
// C = scale*(A@B) [+ bias], computed as Ah*Bh + Ah*Bl + Al*Bh on bf16 MFMA.
// Block tile 128x256, 512 threads = 8 waves (2 x 4), wave tile 64x64
// (4x4 of 16x16x32), BK=32. TRIPLE-buffered LDS (144 KB, 1 block/CU):
// restage target at kt is buf[(kt+2)%3] whose readers drained at kt-1 ->
// ONE barrier per K-step; counted vmcnt(6), vmcnt(0) only at tail; setprio
// around the MFMA cluster.
// R9 change: REMOVED the pinned lgkmcnt(0)+sched_barrier between frag reads
// and MFMAs. It forced all 16 ds_read_b128 to drain before any MFMA
// (serialized ~384cy reads + ~466cy MFMA per SIMD -> the 30% plateau).
// Compiler-managed deps emit fine-grained lgkmcnt(4/3/1/0) and interleave
// read-issue with MFMA-issue (m97 disasm; m141: pinning costs ~40%).
// Safety: frag reads of buf[cb] are consumed by this step's MFMAs (compiler
// waits precede consumers), MFMAs precede next s_barrier, and the restage
// overwriting buf[cb] issues only after that barrier. The sched_barrier(0)
// AFTER each s_barrier stays (stops reads hoisting above staging barrier).
// OUTM: 0 = fp32 C (o1)    1 = qkv epilogue (o1..o5 = Qh,Ql,Kh,Kl,Vfp32)
//       2 = hi/lo bf16 (o1,o2)
// ROWSCALE (OUTM=2): per-row scale from (const float*)o3 [z*1024+row].
template<int OUTM, bool HAS_BIAS, bool ROWSCALE>
__global__ __launch_bounds__(512, 2)
void mgemm(const unsigned short* __restrict__ Ah_, const unsigned short* __restrict__ Al_,
           const unsigned short* __restrict__ Bh_, const unsigned short* __restrict__ Bl_,
           const float* __restrict__ bias,
           void* o1, void* o2, void* o3, void* o4, void* o5,
           int K, int lda, int ldc,
           long long sA, long long sB, long long sC, float scale)
{
    const int tid = threadIdx.x;
    const int bm = blockIdx.y * 128;
    const int bn = blockIdx.x * 256;
    const long long z = blockIdx.z;

    const unsigned short* Ahu = Ah_ + z * sA;
    const unsigned short* Alu = Al_ + z * sA;
    const unsigned short* Bhu = Bh_ + z * sB;
    const unsigned short* Blu = Bl_ + z * sB;

    __shared__ unsigned short LA_h[3][4096], LA_l[3][4096];   // 8 blks x 512
    __shared__ unsigned short LB_h[3][8192], LB_l[3][8192];   // 16 blks x 512

    const int wv = tid >> 6, lane = tid & 63;
    const int wr = wv >> 2, wc = wv & 3;                  // 2 x 4 wave grid
    const int fro = (lane >> 4) * 128 + (lane & 15) * 8;  // frag offset in blk

    const int srow = lane & 15, skg = lane >> 4;
    const size_t gaA  = (size_t)(bm + 16 * wv + srow) * lda + skg * 8;
    const size_t gaB0 = (size_t)(bn + 32 * wv + srow) * lda + skg * 8;
    const size_t gaB1 = (size_t)(bn + 32 * wv + 16 + srow) * lda + skg * 8;
    const int loA = wv * 512, loB = wv * 1024;

    auto stage = [&](int bb, int k0) {   // 6 x global_load_lds_dwordx4 / wave
        gl2lds16(&Ahu[gaA  + k0], &LA_h[bb][loA]);
        gl2lds16(&Alu[gaA  + k0], &LA_l[bb][loA]);
        gl2lds16(&Bhu[gaB0 + k0], &LB_h[bb][loB]);
        gl2lds16(&Bhu[gaB1 + k0], &LB_h[bb][loB + 512]);
        gl2lds16(&Blu[gaB0 + k0], &LB_l[bb][loB]);
        gl2lds16(&Blu[gaB1 + k0], &LB_l[bb][loB + 512]);
    };

    f32x4 acc[4][4];
#pragma unroll
    for (int i = 0; i < 4; ++i)
#pragma unroll
        for (int j = 0; j < 4; ++j) acc[i][j] = (f32x4){0.f, 0.f, 0.f, 0.f};

    const int nkt = K >> 5;      // >= 24 at all call sites
    stage(0, 0);
    stage(1, 32);
    for (int kt = 0; kt < nkt; ++kt) {
        const int cb = kt % 3;
        if (kt < nkt - 1) {
            asm volatile("s_waitcnt vmcnt(6)" ::: "memory");
        } else {
            asm volatile("s_waitcnt vmcnt(0)" ::: "memory");
        }
        __builtin_amdgcn_sched_barrier(0);
        __builtin_amdgcn_s_barrier();            // buf[cb] landed;
        __builtin_amdgcn_sched_barrier(0);       // buf[(kt+2)%3] fully drained

        if (kt + 2 < nkt) stage((kt + 2) % 3, (kt + 2) << 5);

        bf16x8 bhf[4], blf[4], ahf[4], alf[4];
#pragma unroll
        for (int ni = 0; ni < 4; ++ni) {
            int off = (wc * 4 + ni) * 512 + fro;
            bhf[ni] = *(const bf16x8*)&LB_h[cb][off];
            blf[ni] = *(const bf16x8*)&LB_l[cb][off];
        }
#pragma unroll
        for (int mi = 0; mi < 4; ++mi) {
            int off = (wr * 4 + mi) * 512 + fro;
            ahf[mi] = *(const bf16x8*)&LA_h[cb][off];
            alf[mi] = *(const bf16x8*)&LA_l[cb][off];
        }
        // (no lgkmcnt fence here -- compiler interleaves reads with MFMAs)

        __builtin_amdgcn_s_setprio(1);
#pragma unroll
        for (int mi = 0; mi < 4; ++mi) {
#pragma unroll
            for (int ni = 0; ni < 4; ++ni) {
                f32x4 a = acc[mi][ni];
                a = __builtin_amdgcn_mfma_f32_16x16x32_bf16(ahf[mi], bhf[ni], a, 0, 0, 0);
                a = __builtin_amdgcn_mfma_f32_16x16x32_bf16(ahf[mi], blf[ni], a, 0, 0, 0);
                a = __builtin_amdgcn_mfma_f32_16x16x32_bf16(alf[mi], bhf[ni], a, 0, 0, 0);
                acc[mi][ni] = a;
            }
        }
        __builtin_amdgcn_s_setprio(0);
    }

    // ---- epilogue: C/D layout col=lane&15, row=(lane>>4)*4+r ----
#pragma unroll
    for (int mi = 0; mi < 4; ++mi) {
#pragma unroll
        for (int ni = 0; ni < 4; ++ni) {
            const int grow0 = bm + wr * 64 + mi * 16 + ((lane >> 4) << 2);
            const int gcol  = bn + wc * 64 + ni * 16 + (lane & 15);
            float bb = HAS_BIAS ? bias[gcol] : 0.f;
#pragma unroll
            for (int r = 0; r < 4; ++r) {
                const int grow = grow0 + r;
                float sc2 = scale;
                if (ROWSCALE) sc2 = ((const float*)o3)[z * 1024 + grow];
                float v = acc[mi][ni][r] * sc2 + bb;
                const size_t growz = (size_t)grow;
                if (OUTM == 0) {
                    ((float*)o1 + z * sC)[growz * ldc + gcol] = v;
                } else if (OUTM == 1) {
                    if (gcol < 768) {
                        unsigned short h = bf16_rn(v);
                        ((unsigned short*)o1)[growz * 768 + gcol] = h;
                        ((unsigned short*)o2)[growz * 768 + gcol] = bf16_rn(v - bf16f(h));
                    } else if (gcol < 1536) {
                        int cc = gcol - 768;
                        unsigned short h = bf16_rn(v);
                        ((unsigned short*)o3)[growz * 768 + cc] = h;
                        ((unsigned short*)o4)[growz * 768 + cc] = bf16_rn(v - bf16f(h));
                    } else {
                        ((float*)o5)[growz * 768 + (gcol - 1536)] = v;
                    }
                } else {
                    unsigned short h = bf16_rn(v);
                    ((unsigned short*)o1 + z * sC)[growz * ldc + gcol] = h;
                    ((unsigned short*)o2 + z * sC)[growz * ldc + gcol] = bf16_rn(v - bf16f(h));
                }
            }
        }
    }
}

// ==================== fused S + G + modulation kernel ======================
// smod: S-tile = Q@K^T (same core, fence removed), then G = gw_q.gw_k via
// MFMA (K=64 zero-padded, frags straight from global/L2), then
// w = exp(s*scale)*g written as bf16 hi/lo; per-row T=Σw, Z=Σe, SG=Σg
// atomicAdd'd. m (row max) is mathematically arbitrary (attn exactly
// m-invariant incl. both eps terms); |s| <= 28 << 88 -> m=0 safe.
__global__ __launch_bounds__(512, 2)
void smod(const unsigned short* __restrict__ Ah_, const unsigned short* __restrict__ Al_,
          const unsigned short* __restrict__ Bh_, const unsigned short* __restrict__ Bl_,
          const unsigned short* __restrict__ gwH, const unsigned short* __restrict__ gwL,
          unsigned short* __restrict__ Sh, unsigned short* __restrict__ Sl,
          float* __restrict__ Tv, float* __restrict__ Zv, float* __restrict__ Gv,
          float scale)
{
    const int tid = threadIdx.x;
    const int bm = blockIdx.y * 128;
    const int bn = blockIdx.x * 256;
    const long long z = blockIdx.z;
    const int lda = 768;

    const unsigned short* Ahu = Ah_ + z * 1024ll * 768;
    const unsigned short* Alu = Al_ + z * 1024ll * 768;
    const unsigned short* Bhu = Bh_ + z * 1024ll * 768;
    const unsigned short* Blu = Bl_ + z * 1024ll * 768;

    __shared__ unsigned short LA_h[3][4096], LA_l[3][4096];
    __shared__ unsigned short LB_h[3][8192], LB_l[3][8192];

    const int wv = tid >> 6, lane = tid & 63;
    const int wr = wv >> 2, wc = wv & 3;
    const int fro = (lane >> 4) * 128 + (lane & 15) * 8;
    const int l15 = lane & 15, l4 = lane >> 4;

    const size_t gaA  = (size_t)(bm + 16 * wv + l15) * lda + l4 * 8;
    const size_t gaB0 = (size_t)(bn + 32 * wv + l15) * lda + l4 * 8;
    const size_t gaB1 = (size_t)(bn + 32 * wv + 16 + l15) * lda + l4 * 8;
    const int loA = wv * 512, loB = wv * 1024;

    auto stage = [&](int bb, int k0) {
        gl2lds16(&Ahu[gaA  + k0], &LA_h[bb][loA]);
        gl2lds16(&Alu[gaA  + k0], &LA_l[bb][loA]);
        gl2lds16(&Bhu[gaB0 + k0], &LB_h[bb][loB]);
        gl2lds16(&Bhu[gaB1 + k0], &LB_h[bb][loB + 512]);
        gl2lds16(&Blu[gaB0 + k0], &LB_l[bb][loB]);
        gl2lds16(&Blu[gaB1 + k0], &LB_l[bb][loB + 512]);
    };

    f32x4 acc[4][4];
#pragma unroll
    for (int i = 0; i < 4; ++i)
#pragma unroll
        for (int j = 0; j < 4; ++j) acc[i][j] = (f32x4){0.f, 0.f, 0.f, 0.f};

    const int nkt = 768 >> 5;    // 24
    stage(0, 0);
    stage(1, 32);
    for (int kt = 0; kt < nkt; ++kt) {
        const int cb = kt % 3;
        if (kt < nkt - 1) {
            asm volatile("s_waitcnt vmcnt(6)" ::: "memory");
        } else {
            asm volatile("s_waitcnt vmcnt(0)" ::: "memory");
        }
        __builtin_amdgcn_sched_barrier(0);
        __builtin_amdgcn_s_barrier();
        __builtin_amdgcn_sched_barrier(0);

        if (kt + 2 < nkt) stage((kt + 2) % 3, (kt + 2) << 5);

        bf16x8 bhf[4], blf[4], ahf[4], alf[4];
#pragma unroll
        for (int ni = 0; ni < 4; ++ni) {
            int off = (wc * 4 + ni) * 512 + fro;
            bhf[ni] = *(const bf16x8*)&LB_h[cb][off];
            blf[ni] = *(const bf16x8*)&LB_l[cb][off];
        }
#pragma unroll
        for (int mi = 0; mi < 4; ++mi) {
            int off = (wr * 4 + mi) * 512 + fro;
            ahf[mi] = *(const bf16x8*)&LA_h[cb][off];
            alf[mi] = *(const bf16x8*)&LA_l[cb][off];
        }
        // (no lgkmcnt fence -- compiler interleaves reads with MFMAs)

        __builtin_amdgcn_s_setprio(1);
#pragma unroll
        for (int mi = 0; mi < 4; ++mi) {
#pragma unroll
            for (int ni = 0; ni < 4; ++ni) {
                f32x4 a = acc[mi][ni];
                a = __builtin_amdgcn_mfma_f32_16x16x32_bf16(ahf[mi], bhf[ni], a, 0, 0, 0);
                a = __builtin_amdgcn_mfma_f32_16x16x32_bf16(ahf[mi], blf[ni], a, 0, 0, 0);
                a = __builtin_amdgcn_mfma_f32_16x16x32_bf16(alf[mi], bhf[ni], a, 0, 0, 0);
                acc[mi][ni] = a;
            }
        }
        __builtin_amdgcn_s_setprio(0);
    }

    // ---- fused epilogue: G via MFMA + w = exp(s*scale)*g ----
    const long long gwz = z * 1024 * 64;
    float Tp[16], Zp[16], Gp[16];
#pragma unroll
    for (int s = 0; s < 16; ++s) { Tp[s] = 0.f; Zp[s] = 0.f; Gp[s] = 0.f; }

    unsigned short* ShZ = Sh + z * 1024ll * 1024;
    unsigned short* SlZ = Sl + z * 1024ll * 1024;

#pragma unroll
    for (int mi = 0; mi < 4; ++mi) {
        bf16x8 gah[2], gal[2];
#pragma unroll
        for (int kt = 0; kt < 2; ++kt) {
            long long ga = gwz + (long long)(bm + wr * 64 + mi * 16 + l15) * 64
                         + kt * 32 + l4 * 8;
            gah[kt] = *(const bf16x8*)&gwH[ga];
            gal[kt] = *(const bf16x8*)&gwL[ga];
        }
#pragma unroll
        for (int ni = 0; ni < 4; ++ni) {
            bf16x8 gbh[2], gbl[2];
#pragma unroll
            for (int kt = 0; kt < 2; ++kt) {
                long long gb = gwz + (long long)(bn + wc * 64 + ni * 16 + l15) * 64
                             + kt * 32 + l4 * 8;
                gbh[kt] = *(const bf16x8*)&gwH[gb];
                gbl[kt] = *(const bf16x8*)&gwL[gb];
            }
            f32x4 g4 = (f32x4){0.f, 0.f, 0.f, 0.f};
#pragma unroll
            for (int kt = 0; kt < 2; ++kt) {
                g4 = __builtin_amdgcn_mfma_f32_16x16x32_bf16(gah[kt], gbh[kt], g4, 0, 0, 0);
                g4 = __builtin_amdgcn_mfma_f32_16x16x32_bf16(gah[kt], gbl[kt], g4, 0, 0, 0);
                g4 = __builtin_amdgcn_mfma_f32_16x16x32_bf16(gal[kt], gbh[kt], g4, 0, 0, 0);
            }
            const int col = bn + wc * 64 + ni * 16 + l15;
#pragma unroll
            for (int r = 0; r < 4; ++r) {
                const int row = bm + wr * 64 + mi * 16 + l4 * 4 + r;
                float e = expf(acc[mi][ni][r] * scale);   // m = 0 (invariant)
                float g = g4[r];
                float w = e * g;
                Tp[mi * 4 + r] += w;
                Zp[mi * 4 + r] += e;
                Gp[mi * 4 + r] += g;
                unsigned short h = bf16_rn(w);
                ShZ[(size_t)row * 1024 + col] = h;
                SlZ[(size_t)row * 1024 + col] = bf16_rn(w - bf16f(h));
            }
        }
    }
    // reduce over the 16 lanes sharing each row (lane bits 0-3 = cols)
#pragma unroll
    for (int s = 0; s < 16; ++s) {
#pragma unroll
        for (int off = 1; off < 16; off <<= 1) {
            Tp[s] += __shfl_xor(Tp[s], off);
            Zp[s] += __shfl_xor(Zp[s], off);
            Gp[s] += __shfl_xor(Gp[s], off);
        }
    }
    if (l15 == 0) {
        float* TvZ = Tv + z * 1024;
        float* ZvZ = Zv + z * 1024;
        float* GvZ = Gv + z * 1024;
#pragma unroll
        for (int mi = 0; mi < 4; ++mi)
#pragma unroll
            for (int r = 0; r < 4; ++r) {
                const int row = bm + wr * 64 + mi * 16 + l4 * 4 + r;
                atomicAdd(&TvZ[row], Tp[mi * 4 + r]);
                atomicAdd(&ZvZ[row], Zp[mi * 4 + r]);
                atomicAdd(&GvZ[row], Gp[mi * 4 + r]);
            }
    }
}

// ==================== elementwise fp32 -> hi/lo bf16 split =================
__global__ __launch_bounds__(256)
void split_k(const float* __restrict__ src, unsigned short* __restrict__ dh,
             unsigned short* __restrict__ dl, long long n8)
{
    long long i = (long long)blockIdx.x * 256 + threadIdx.x;
    const long long stride = (long long)gridDim.x * 256;
    for (; i < n8; i += stride) {
        const float4* p = (const float4*)(src + i * 8);
        float4 f0 = p[0], f1 = p[1];
        float ff[8] = {f0.x, f0.y, f0.z, f0.w, f1.x, f1.y, f1.z, f1.w};
        bf16x8 hv, lv;
#pragma unroll
        for (int j = 0; j < 8; ++j) {
            unsigned short h = bf16_rn(ff[j]);
            hv[j] = (short)h;
            lv[j] = (short)bf16_rn(ff[j] - bf16f(h));
        }
        *(bf16x8*)(dh + i * 8) = hv;
        *(bf16x8*)(dl + i * 8) = lv;
    }
}

// ==================== transpose + split to hi/lo bf16 ======================
__global__ __launch_bounds__(256)
void tsplit_k(const float* __restrict__ src, unsigned short* __restrict__ dh,
              unsigned short* __restrict__ dl, int ls, long long ss,
              int ld_, long long sd)
{
    src += (long long)blockIdx.z * ss;
    dh  += (long long)blockIdx.z * sd;
    dl  += (long long)blockIdx.z * sd;
    __shared__ float t[32][33];
    const int tx = threadIdx.x & 31, ty = threadIdx.x >> 5;
    const int r0 = blockIdx.y * 32, c0 = blockIdx.x * 32;
#pragma unroll
    for (int i = 0; i < 4; ++i)
        t[ty + 8 * i][tx] = src[(size_t)(r0 + ty + 8 * i) * ls + c0 + tx];
    __syncthreads();
#pragma unroll
    for (int i = 0; i < 4; ++i) {
        float v = t[tx][ty + 8 * i];
        unsigned short h = bf16_rn(v);
        size_t o = (size_t)(c0 + ty + 8 * i) * ld_ + r0 + tx;
        dh[o] = h;
        dl[o] = bf16_rn(v - bf16f(h));
    }
}

// ==================== gw = softmax(V @ w_gp) -> hi/lo bf16, padded to 64 ===
__global__ __launch_bounds__(64)
void gw_k(const float* __restrict__ Vf, const float* __restrict__ wgp,
          unsigned short* __restrict__ gh, unsigned short* __restrict__ gl)
{
    const long long row = blockIdx.x;
    const int lane = threadIdx.x;
    const float* v = Vf + row * 768;
    float a0 = 0.f, a1 = 0.f, a2 = 0.f, a3 = 0.f;
    if (lane < 49) {
        for (int d = 0; d < 768; d += 4) {
            float4 vv = *(const float4*)&v[d];
            a0 = fmaf(vv.x, wgp[(d + 0) * 49 + lane], a0);
            a1 = fmaf(vv.y, wgp[(d + 1) * 49 + lane], a1);
            a2 = fmaf(vv.z, wgp[(d + 2) * 49 + lane], a2);
            a3 = fmaf(vv.w, wgp[(d + 3) * 49 + lane], a3);
        }
    }
    float logit = (lane < 49) ? ((a0 + a1) + (a2 + a3)) : -INFINITY;
    float m = logit;
    for (int off = 32; off; off >>= 1) m = fmaxf(m, __shfl_xor(m, off));
    float e = (lane < 49) ? expf(logit - m) : 0.f;
    float s = e;
    for (int off = 32; off; off >>= 1) s += __shfl_xor(s, off);
    float val = e / s;                       // 0 for pad lanes 49..63
    unsigned short h = bf16_rn(val);
    gh[row * 64 + lane] = h;
    gl[row * 64 + lane] = bf16_rn(val - bf16f(h));
}

// ==================== zero-init for T/Z/SG accumulators ====================
__global__ __launch_bounds__(256)
void zinit_k(float* __restrict__ p, int n)
{
    int i = blockIdx.x * 256 + threadIdx.x;
    if (i < n) p[i] = 0.f;
}

// ==================== f = c/(cT+eps), c = n/(Z(SG+eps)) ====================
__global__ __launch_bounds__(256)
void fcomp_k(const float* __restrict__ Tv, const float* __restrict__ Zv,
             const float* __restrict__ Gv, float* __restrict__ fvec, int n)
{
    int i = blockIdx.x * 256 + threadIdx.x;
    if (i < n) {
        float c = 1024.f / (Zv[i] * (Gv[i] + 1e-8f));
        fvec[i] = c / (c * Tv[i] + 1e-8f);
    }
}

// ==================== launcher =============================================
extern "C" void kernel_launch(void* const* d_in, const int* in_sizes, int n_in,
                              void* d_out, int out_size, void* d_ws, size_t ws_size,
                              hipStream_t stream)
{
    const float* x      = (const float*)d_in[0];   // [32,1024,768]
    const float* w_qkv  = (const float*)d_in[1];   // [768,2304]
    const float* b_qkv  = (const float*)d_in[2];   // [2304]
    const float* w_proj = (const float*)d_in[3];   // [768,768]
    const float* b_proj = (const float*)d_in[4];   // [768]
    const float* w_gp   = (const float*)d_in[5];   // [768,49]
    float* out = (float*)d_out;

    auto need = [](int CB) -> size_t {
        size_t u = 0;
        u += 2ull * 2304 * 768;            // WqT h+l
        u += 2ull * 768 * 768;             // WpT h+l
        u += 4ull * CB * 1024 * 768;       // Qh,Ql,Kh,Kl (O aliases Q)
        u += 2ull * CB * 1024 * 768;       // VTh,VTl
        u += 2ull * CB * 1024 * 1024;      // Sh,Sl (aliased as Xh,Xl)
        u += 2ull * CB * 1024 * 64;        // gwH,gwL
        size_t bytes = u * 2;
        bytes += 4ull * ((size_t)CB * 1024 * 768      // Vf
                       + 5ull * CB * 1024);           // Tv,Zv,Gv,fvec + pad
        return bytes + 8192;
    };
    int CB = 32;
    while (CB > 1 && need(CB) > ws_size) CB >>= 1;
    const int MC = CB * 1024;

    char* cur = (char*)d_ws;
    auto alloc_u = [&](size_t n) {
        unsigned short* p = (unsigned short*)cur;
        cur += ((n * 2 + 15) & ~15ull);
        return p;
    };
    auto alloc_f = [&](size_t n) {
        float* p = (float*)cur;
        cur += ((n * 4 + 15) & ~15ull);
        return p;
    };
    unsigned short* WqTh = alloc_u(2304ull * 768);
    unsigned short* WqTl = alloc_u(2304ull * 768);
    unsigned short* WpTh = alloc_u(768ull * 768);
    unsigned short* WpTl = alloc_u(768ull * 768);
    unsigned short* Qh   = alloc_u((size_t)MC * 768);
    unsigned short* Ql   = alloc_u((size_t)MC * 768);
    unsigned short* Kh   = alloc_u((size_t)MC * 768);
    unsigned short* Kl   = alloc_u((size_t)MC * 768);
    unsigned short* VTh  = alloc_u((size_t)MC * 768);
    unsigned short* VTl  = alloc_u((size_t)MC * 768);
    unsigned short* Sh   = alloc_u((size_t)MC * 1024);
    unsigned short* Sl   = alloc_u((size_t)MC * 1024);
    unsigned short* gwH  = alloc_u((size_t)MC * 64);
    unsigned short* gwL  = alloc_u((size_t)MC * 64);
    float* Vf   = alloc_f((size_t)MC * 768);
    float* Tv   = alloc_f((size_t)MC);
    float* Zv   = alloc_f((size_t)MC);
    float* Gv   = alloc_f((size_t)MC);
    float* fvec = alloc_f((size_t)MC);
    unsigned short* Oh = Qh;   // O aliases Q (Q dead after S=QK^T)
    unsigned short* Ol = Ql;
    unsigned short* Xh = Sh;   // x split aliases S (dead after step 1)
    unsigned short* Xl = Sl;

    const float scale = 1.0f / sqrtf(768.0f);

    // ---- weight prep (once per launch) ----
    tsplit_k<<<dim3(72, 24, 1), 256, 0, stream>>>(w_qkv, WqTh, WqTl, 2304, 0, 768, 0);
    tsplit_k<<<dim3(24, 24, 1), 256, 0, stream>>>(w_proj, WpTh, WpTl, 768, 0, 768, 0);

    for (int c = 0; c < 32 / CB; ++c) {
        const float* xc   = x   + (size_t)c * MC * 768;
        float*       outc = out + (size_t)c * MC * 768;

        // 0) split x -> hi/lo bf16
        {
            const long long n8 = (long long)MC * 768 / 8;
            int nb = (int)((n8 + 255) / 256);
            if (nb > 4096) nb = 4096;
            split_k<<<dim3(nb), 256, 0, stream>>>(xc, Xh, Xl, n8);
        }

        // 1) qkv GEMM: A = Xh/Xl, B = WqT -> Qh/Ql, Kh/Kl, Vf   (N=2304)
        mgemm<1, true, false><<<dim3(9, MC / 128, 1), 512, 0, stream>>>(
            Xh, Xl, WqTh, WqTl, b_qkv,
            Qh, Ql, Kh, Kl, Vf, 768, 768, 0, 0, 0, 0, 1.0f);

        // 2) gw = softmax(V @ w_gp) -> hi/lo bf16 padded to 64
        gw_k<<<dim3(MC), 64, 0, stream>>>(Vf, w_gp, gwH, gwL);

        // 3) V^T hi/lo per batch
        tsplit_k<<<dim3(24, 32, CB), 256, 0, stream>>>(
            Vf, VTh, VTl, 768, 1024ll * 768, 1024, 768ll * 1024);

        // 3b) zero T/Z/SG accumulators (contiguous: Tv,Zv,Gv)
        zinit_k<<<dim3((3 * MC + 255) / 256), 256, 0, stream>>>(Tv, 3 * MC);

        // 4) fused S=QK^T + G + w=exp(s)*g -> Sh/Sl; T/Z/SG atomics
        smod<<<dim3(4, 8, CB), 512, 0, stream>>>(
            Qh, Ql, Kh, Kl, gwH, gwL, Sh, Sl, Tv, Zv, Gv, scale);

        // 5) f per row from T/Z/SG
        fcomp_k<<<dim3((MC + 255) / 256), 256, 0, stream>>>(Tv, Zv, Gv, fvec, MC);

        // 6) O = (w @ V) * f (per batch, row-scaled epilogue) -> Oh/Ol
        mgemm<2, false, true><<<dim3(3, 8, CB), 512, 0, stream>>>(
            Sh, Sl, VTh, VTl, nullptr,
            Oh, Ol, fvec, nullptr, nullptr,
            1024, 1024, 768, 1024ll * 1024, 768ll * 1024, 1024ll * 768, 1.0f);

        // 7) out = O @ w_proj + b_proj
        mgemm<0, true, false><<<dim3(3, MC / 128, 1), 512, 0, stream>>>(
            Oh, Ol, WpTh, WpTl, b_proj,
            outc, nullptr, nullptr, nullptr, nullptr,
            768, 768, 768, 0, 0, 0, 1.0f);
    }
}